// Round 1
// baseline (610.403 us; speedup 1.0000x reference)
//
#include <hip/hip_runtime.h>
#include <hip/hip_bf16.h>

// Problem constants (from reference):
//   B=512, GS=2048, PARAM=64, C=2, OGS=1024, PARAMO=64
//   x: (512, 2048, 64) f32, trafo: (128, 64) f32
//   out: (512, 1024, 64) f32
#define BATCH  512
#define GSZ    2048
#define PAR    64
#define OGS    1024
#define KDIM   128   // PARAM*C
#define NDIM   64    // PARAMO

// ---------------------------------------------------------------------------
// Kernel 1: per-batch stable descending sort of x[:,:,63] -> order permutation
// Bitonic sort on packed 64-bit keys in LDS.
// key = (~monotonic(fp32bits) << 32) | index
//   ascending u64 order == descending float order, ties -> lower index first
//   (matches jax.lax.top_k stability).
// ---------------------------------------------------------------------------
__global__ __launch_bounds__(1024) void sort_kernel(
    const float* __restrict__ x, int* __restrict__ order) {
    __shared__ unsigned long long keys[GSZ];
    const int b = blockIdx.x;
    const int t = threadIdx.x;
    const float* xb = x + (size_t)b * GSZ * PAR;

    #pragma unroll
    for (int s = 0; s < 2; ++s) {
        int i = t + s * 1024;
        float v = xb[(size_t)i * PAR + (PAR - 1)];
        unsigned u = __float_as_uint(v);
        u = (u & 0x80000000u) ? ~u : (u | 0x80000000u); // ascending monotonic
        u = ~u;                                          // descending
        keys[i] = ((unsigned long long)u << 32) | (unsigned)i;
    }
    __syncthreads();

    for (int k = 2; k <= GSZ; k <<= 1) {
        for (int j = k >> 1; j > 0; j >>= 1) {
            #pragma unroll
            for (int s = 0; s < 2; ++s) {
                int i = t + s * 1024;
                int ixj = i ^ j;
                if (ixj > i) {
                    bool up = ((i & k) == 0);
                    unsigned long long a = keys[i];
                    unsigned long long c = keys[ixj];
                    if ((a > c) == up) { keys[i] = c; keys[ixj] = a; }
                }
            }
            __syncthreads();
        }
    }

    #pragma unroll
    for (int s = 0; s < 2; ++s) {
        int i = t + s * 1024;
        order[b * GSZ + i] = (int)(keys[i] & 0xffffffffu);
    }
}

// ---------------------------------------------------------------------------
// Kernel 2: fused gather + GEMM.
// Block = 256 threads (4 waves), tile = 128 xs-rows x 64 cols (full N).
// xs row g = concat( x[b, order[2g], :], x[b, order[2g+1], :] )  (128 floats)
// LDS xt stored [k][row] (column-major wrt GEMM) padded to 129 so the
// per-k lane read xt[k][rbase+lane] is bank-conflict-free (129 % 32 == 1).
// Wave w: rows (w&1)*64 .. +63 (lane == local row), cols (w>>1)*32 .. +31.
// trafo accessed with wave-uniform indices -> scalar loads (SGPR operand FMA).
// ---------------------------------------------------------------------------
#define TM 128                 // xs-rows per block
#define ROWPAD 129

__global__ __launch_bounds__(256) void gather_gemm_kernel(
    const float* __restrict__ x, const float* __restrict__ trafo,
    const int* __restrict__ order, float* __restrict__ out) {
    __shared__ float xt[KDIM][ROWPAD];   // 128 x 129 x 4B = 66048 B

    const int b    = blockIdx.x >> 3;          // 8 row-tiles per batch
    const int tile = blockIdx.x & 7;
    const int g0   = tile * TM;                // first xs-row of tile
    const int t    = threadIdx.x;

    const float* xb = x + (size_t)b * GSZ * PAR;
    const int* ob   = order + b * GSZ + 2 * g0; // 256 source-row slots

    // ---- stage: gather 256 source x-rows (64 f32 each) into LDS ----
    // loadidx l in [0,4096): slot = l>>4 (source slot), f4 = l&15 (float4 in row)
    #pragma unroll
    for (int i = 0; i < 16; ++i) {
        int l    = t + i * 256;
        int slot = l >> 4;          // 0..255 ; xs-row = slot>>1, half = slot&1
        int f4   = l & 15;
        int src  = ob[slot];
        const float4 v = *reinterpret_cast<const float4*>(
            xb + (size_t)src * PAR + f4 * 4);
        int krow = (slot & 1) * PAR + f4 * 4;   // k index of v.x
        int row  = slot >> 1;                   // local xs-row 0..127
        xt[krow + 0][row] = v.x;
        xt[krow + 1][row] = v.y;
        xt[krow + 2][row] = v.z;
        xt[krow + 3][row] = v.w;
    }
    __syncthreads();

    // ---- compute ----
    const int w     = t >> 6;
    const int lane  = t & 63;
    const int rbase = (w & 1) * 64;
    const int cbase = __builtin_amdgcn_readfirstlane((w >> 1) * 32);

    float acc[32];
    #pragma unroll
    for (int c = 0; c < 32; ++c) acc[c] = 0.0f;

    #pragma unroll 2
    for (int k = 0; k < KDIM; ++k) {
        float a = xt[k][rbase + lane];
        const float* tr = trafo + k * NDIM + cbase;   // wave-uniform address
        #pragma unroll
        for (int c = 0; c < 32; ++c) acc[c] = fmaf(a, tr[c], acc[c]);
    }

    // ---- epilogue: out[b][g0 + rbase + lane][cbase + 0..31] ----
    float* op = out + ((size_t)b * OGS + g0 + rbase + lane) * NDIM + cbase;
    #pragma unroll
    for (int c4 = 0; c4 < 8; ++c4) {
        float4 v = make_float4(acc[c4 * 4 + 0], acc[c4 * 4 + 1],
                               acc[c4 * 4 + 2], acc[c4 * 4 + 3]);
        *reinterpret_cast<float4*>(op + c4 * 4) = v;
    }
}

extern "C" void kernel_launch(void* const* d_in, const int* in_sizes, int n_in,
                              void* d_out, int out_size, void* d_ws, size_t ws_size,
                              hipStream_t stream) {
    const float* x     = (const float*)d_in[0];   // (512, 2048, 64) f32
    const float* trafo = (const float*)d_in[1];   // (128, 64) f32
    float* out         = (float*)d_out;           // (512, 1024, 64) f32
    int* order         = (int*)d_ws;              // 512*2048 ints = 4 MiB

    sort_kernel<<<BATCH, 1024, 0, stream>>>(x, order);
    gather_gemm_kernel<<<BATCH * (OGS / TM), 256, 0, stream>>>(x, trafo, order, out);
}

// Round 2
// 459.508 us; speedup vs baseline: 1.3284x; 1.3284x over previous
//
#include <hip/hip_runtime.h>
#include <hip/hip_bf16.h>

// Problem: B=512, GS=2048, PARAM=64, C=2, OGS=1024, PARAMO=64
//   x: (512, 2048, 64) f32, trafo: (128, 64) f32, out: (512, 1024, 64) f32
#define BATCH  512
#define GSZ    2048
#define PAR    64
#define OGS    1024
#define KDIM   128
#define NDIM   64

// ---------------------------------------------------------------------------
// Kernel 1: stable LSD radix sort (4 passes x 8 bits) of descending-transformed
// f32 keys, payload = index. LSD stability == top_k tie semantics (lower index
// first) because the initial array is in index order.
// Block: 1024 threads = 16 waves; 2048 elements (2 per thread).
// Per pass: per-wave ballot-built digit match mask -> within-chunk rank via
// mbcnt; one leader per (chunk,digit) writes the chunk histogram; two-level
// exclusive scan (over chunks within digit, then over digits); stable scatter.
// ---------------------------------------------------------------------------
__global__ __launch_bounds__(1024) void radix_sort_kernel(
    const float* __restrict__ x, int* __restrict__ order) {
    __shared__ unsigned keyA[GSZ], payA[GSZ], keyB[GSZ], payB[GSZ];
    __shared__ unsigned hist[32][256];        // [chunk][digit]
    __shared__ unsigned totals[256], base[256], wtot[4];

    const int b = blockIdx.x;
    const int t = threadIdx.x;
    const int w = t >> 6, lane = t & 63;

    #pragma unroll
    for (int s = 0; s < 2; ++s) {
        int i = t + s * 1024;
        unsigned u = __float_as_uint(x[(size_t)b * GSZ * PAR + (size_t)i * PAR + (PAR - 1)]);
        u = (u & 0x80000000u) ? ~u : (u | 0x80000000u); // ascending monotonic
        keyA[i] = ~u;                                    // descending value
        payA[i] = (unsigned)i;
    }
    __syncthreads();

    for (int pass = 0; pass < 4; ++pass) {
        const int sh = pass * 8;
        unsigned* ksrc = (pass & 1) ? keyB : keyA;
        unsigned* psrc = (pass & 1) ? payB : payA;
        unsigned* kdst = (pass & 1) ? keyA : keyB;
        unsigned* pdst = (pass & 1) ? payA : payB;

        // zero histogram
        #pragma unroll
        for (int i = 0; i < 8; ++i) ((unsigned*)hist)[t + i * 1024] = 0u;
        __syncthreads();

        unsigned dreg[2], wreg[2];
        #pragma unroll
        for (int s = 0; s < 2; ++s) {
            int e = t + s * 1024;
            int chunk = w + s * 16;
            unsigned k = ksrc[e];
            unsigned dd = (k >> sh) & 255u;
            unsigned long long m = ~0ull;
            #pragma unroll
            for (int bit = 0; bit < 8; ++bit) {
                unsigned long long bb = __ballot((dd >> bit) & 1u);
                m &= ((dd >> bit) & 1u) ? bb : ~bb;
            }
            unsigned within = __builtin_amdgcn_mbcnt_hi(
                (unsigned)(m >> 32), __builtin_amdgcn_mbcnt_lo((unsigned)m, 0u));
            if (within == 0u) hist[chunk][dd] = (unsigned)__popcll(m);
            dreg[s] = dd; wreg[s] = within;
        }
        __syncthreads();

        // exclusive scan over chunks within each digit column; totals per digit
        if (t < 256) {
            unsigned run = 0;
            #pragma unroll
            for (int c = 0; c < 32; ++c) {
                unsigned v = hist[c][t];
                hist[c][t] = run;
                run += v;
            }
            totals[t] = run;
        }
        __syncthreads();

        // exclusive scan of 256 digit totals -> base
        unsigned v256 = 0, inc = 0;
        if (t < 256) {
            v256 = totals[t];
            inc = v256;
            #pragma unroll
            for (int off = 1; off < 64; off <<= 1) {
                unsigned n = __shfl_up(inc, off, 64);
                if (lane >= off) inc += n;
            }
            if (lane == 63) wtot[t >> 6] = inc;
        }
        __syncthreads();
        if (t < 256) {
            unsigned o = 0;
            #pragma unroll
            for (int j = 0; j < 4; ++j) if (j < (t >> 6)) o += wtot[j];
            base[t] = o + inc - v256;   // exclusive
        }
        __syncthreads();

        // stable scatter
        #pragma unroll
        for (int s = 0; s < 2; ++s) {
            int e = t + s * 1024;
            int chunk = w + s * 16;
            unsigned k = ksrc[e];
            unsigned p = psrc[e];
            unsigned dd = dreg[s];
            unsigned r = base[dd] + hist[chunk][dd] + wreg[s];
            if (pass == 3) {
                order[b * GSZ + (int)r] = (int)p;
            } else {
                kdst[r] = k; pdst[r] = p;
            }
        }
        __syncthreads();
    }
}

// ---------------------------------------------------------------------------
// Kernel 2: gather + GEMM, register micro-tiled, K-chunked double-buffered.
// Block 256 threads (4 waves), tile 128 xs-rows x 64 cols.
// Thread (tm = t&15, tn = t>>4) computes micro-tile rows {tm*4..+3, 64+tm*4..+3}
// x cols {tn*4..+3}: acc[8][4].
// A chunk c (32 xs-cols): parity p=c>>1 picks order[2g+p], colbase=(c&1)*32.
// LDS A[buf][kk][row] (stride-1 writes, stride-4 b128 reads: conflict-free).
// B chunk = trafo rows [32c,32c+32) staged flat (L2-hot).
// ---------------------------------------------------------------------------
#define TM 128

__global__ __launch_bounds__(256) void gather_gemm_kernel(
    const float* __restrict__ x, const float* __restrict__ trafo,
    const int* __restrict__ order, float* __restrict__ out) {
    __shared__ float Ash[2][32][TM];   // 2 x 16 KB
    __shared__ float Bsh[32][64];      // 8 KB

    const int b    = blockIdx.x >> 3;
    const int tile = blockIdx.x & 7;
    const int g0   = tile * TM;
    const int t    = threadIdx.x;
    const int tm   = t & 15;
    const int tn   = t >> 4;           // 0..15
    const int row  = t & 127;
    const int rh   = t >> 7;           // 0/1

    const float* xb = x + (size_t)b * GSZ * PAR;
    const int s0 = order[b * GSZ + 2 * (g0 + row) + 0];
    const int s1 = order[b * GSZ + 2 * (g0 + row) + 1];

    // ---- prologue: stage chunk 0 (p=0, cb=0) ----
    {
        const float* sp = xb + (size_t)s0 * PAR + rh * 4;
        float4 n0 = *(const float4*)(sp + 0);
        float4 n1 = *(const float4*)(sp + 8);
        float4 n2 = *(const float4*)(sp + 16);
        float4 n3 = *(const float4*)(sp + 24);
        float4 b0 = ((const float4*)trafo)[t];
        float4 b1 = ((const float4*)trafo)[t + 256];
        #define STW(i, v) { int sub = (i)*2 + rh; \
            Ash[0][sub*4+0][row] = (v).x; Ash[0][sub*4+1][row] = (v).y; \
            Ash[0][sub*4+2][row] = (v).z; Ash[0][sub*4+3][row] = (v).w; }
        STW(0, n0) STW(1, n1) STW(2, n2) STW(3, n3)
        ((float4*)&Bsh[0][0])[t]       = b0;
        ((float4*)&Bsh[0][0])[t + 256] = b1;
    }
    __syncthreads();

    float acc[8][4];
    #pragma unroll
    for (int r = 0; r < 8; ++r)
        #pragma unroll
        for (int c = 0; c < 4; ++c) acc[r][c] = 0.0f;

    int cur = 0;
    for (int c = 0; c < 4; ++c) {
        // issue next chunk's global loads early (latency hides under compute)
        float4 n0, n1, n2, n3, vb0, vb1;
        if (c < 3) {
            const int p  = (c + 1) >> 1;
            const int cb = ((c + 1) & 1) * 32;
            const float* sp = xb + (size_t)(p ? s1 : s0) * PAR + cb + rh * 4;
            n0 = *(const float4*)(sp + 0);
            n1 = *(const float4*)(sp + 8);
            n2 = *(const float4*)(sp + 16);
            n3 = *(const float4*)(sp + 24);
            const float4* tp = (const float4*)(trafo + (size_t)(c + 1) * 32 * 64);
            vb0 = tp[t];
            vb1 = tp[t + 256];
        }

        // compute 32 k-steps from Ash[cur] / Bsh
        #pragma unroll 8
        for (int kk = 0; kk < 32; ++kk) {
            const float4 a0 = *(const float4*)&Ash[cur][kk][tm * 4];
            const float4 a1 = *(const float4*)&Ash[cur][kk][64 + tm * 4];
            const float4 bv = *(const float4*)&Bsh[kk][tn * 4];
            float av[8] = {a0.x, a0.y, a0.z, a0.w, a1.x, a1.y, a1.z, a1.w};
            float bb[4] = {bv.x, bv.y, bv.z, bv.w};
            #pragma unroll
            for (int r = 0; r < 8; ++r)
                #pragma unroll
                for (int cc = 0; cc < 4; ++cc)
                    acc[r][cc] = fmaf(av[r], bb[cc], acc[r][cc]);
        }
        __syncthreads();   // everyone done reading Ash[cur] & Bsh(chunk c)

        if (c < 3) {
            #define STW2(i, v) { int sub = (i)*2 + rh; \
                Ash[cur ^ 1][sub*4+0][row] = (v).x; Ash[cur ^ 1][sub*4+1][row] = (v).y; \
                Ash[cur ^ 1][sub*4+2][row] = (v).z; Ash[cur ^ 1][sub*4+3][row] = (v).w; }
            STW2(0, n0) STW2(1, n1) STW2(2, n2) STW2(3, n3)
            ((float4*)&Bsh[0][0])[t]       = vb0;
            ((float4*)&Bsh[0][0])[t + 256] = vb1;
        }
        __syncthreads();   // staged chunk c+1 visible
        cur ^= 1;
    }

    // ---- epilogue ----
    #pragma unroll
    for (int h = 0; h < 2; ++h) {
        #pragma unroll
        for (int j = 0; j < 4; ++j) {
            const int r = g0 + h * 64 + tm * 4 + j;
            float4 v = make_float4(acc[h * 4 + j][0], acc[h * 4 + j][1],
                                   acc[h * 4 + j][2], acc[h * 4 + j][3]);
            *(float4*)(out + ((size_t)b * OGS + r) * NDIM + tn * 4) = v;
        }
    }
}

extern "C" void kernel_launch(void* const* d_in, const int* in_sizes, int n_in,
                              void* d_out, int out_size, void* d_ws, size_t ws_size,
                              hipStream_t stream) {
    const float* x     = (const float*)d_in[0];   // (512, 2048, 64) f32
    const float* trafo = (const float*)d_in[1];   // (128, 64) f32
    float* out         = (float*)d_out;           // (512, 1024, 64) f32
    int* order         = (int*)d_ws;              // 512*2048 ints = 4 MiB

    radix_sort_kernel<<<BATCH, 1024, 0, stream>>>(x, order);
    gather_gemm_kernel<<<BATCH * (OGS / TM), 256, 0, stream>>>(x, trafo, order, out);
}